// Round 8
// baseline (409.699 us; speedup 1.0000x reference)
//
#include <hip/hip_runtime.h>
#include <math.h>

#define N_PTS 16384
#define DIMS 256
#define HEADS 8
#define HDIM 32
#define KNN 20
#define MLPH 1024
#define SCALE 0.17677669529663687f  // 32^-0.5

typedef unsigned short u16;
typedef __attribute__((ext_vector_type(8))) short bf16x8;
typedef __attribute__((ext_vector_type(8))) unsigned short u16x8;
typedef __attribute__((ext_vector_type(4))) float f32x4;

__device__ __forceinline__ float bf2f(u16 u) {
  return __uint_as_float(((unsigned int)u) << 16);
}
__device__ __forceinline__ u16 f2bf(float f) {
  unsigned int u = __float_as_uint(f);
  u += 0x7fffu + ((u >> 16) & 1u);
  return (u16)(u >> 16);
}
// finite-scrub: NaN/Inf -> 0 (cheap insurance)
__device__ __forceinline__ float fin(float v) {
  return __builtin_isfinite(v) ? v : 0.f;
}
__device__ __forceinline__ float dist2(float4 a, float4 b) {
  float dx = a.x - b.x, dy = a.y - b.y, dz = a.z - b.z;
  return dx * dx + dy * dy + dz * dz;
}
__device__ __forceinline__ u16x8 cvt8(float4 a, float4 b) {
  u16x8 o;
  o[0] = f2bf(a.x); o[1] = f2bf(a.y); o[2] = f2bf(a.z); o[3] = f2bf(a.w);
  o[4] = f2bf(b.x); o[5] = f2bf(b.y); o[6] = f2bf(b.z); o[7] = f2bf(b.w);
  return o;
}

// ---------------- init: zero cnt + nbr ----------------

__global__ __launch_bounds__(256) void init_knn(int* __restrict__ cnt,
                                                int* __restrict__ nbr) {
  int i = blockIdx.x * 256 + threadIdx.x;  // i < N_PTS
  cnt[i] = 0;
#pragma unroll
  for (int j = 0; j < KNN; ++j) nbr[i * KNN + j] = 0;
}

// ---------------- kNN ----------------
// pos4.w holds |c|^2 so screening uses d' = |c|^2 - 2 q.c  (d' = d - |q|^2,
// a per-query constant shift: order statistics per query are unaffected).

__global__ __launch_bounds__(256) void prep_pos(const float* __restrict__ pos,
                                                float4* __restrict__ pos4) {
  int i = blockIdx.x * 256 + threadIdx.x;
  float x = fin(pos[3 * i]), y = fin(pos[3 * i + 1]), z = fin(pos[3 * i + 2]);
  pos4[i] = make_float4(x, y, z, x * x + y * y + z * z);
}

// grid (64 shards, 16 q-groups), block 256, 4 queries/thread.
__global__ __launch_bounds__(256) void knn_shardmin(const float4* __restrict__ pos4,
                                                    float* __restrict__ Mmin) {
  __shared__ float4 cp[256];
  int shard = blockIdx.x;
  int qbase = blockIdx.y * 1024 + threadIdx.x;
  cp[threadIdx.x] = pos4[shard * 256 + threadIdx.x];
  float m2x[4], m2y[4], m2z[4], mn[4];
#pragma unroll
  for (int k = 0; k < 4; ++k) {
    float4 qp = pos4[qbase + k * 256];
    m2x[k] = -2.f * qp.x; m2y[k] = -2.f * qp.y; m2z[k] = -2.f * qp.z;
    mn[k] = 3.4e38f;
  }
  __syncthreads();
#pragma unroll 4
  for (int c = 0; c < 256; ++c) {
    float4 cc = cp[c];
#pragma unroll
    for (int k = 0; k < 4; ++k) {
      float t = fmaf(m2z[k], cc.z, cc.w);
      t = fmaf(m2y[k], cc.y, t);
      t = fmaf(m2x[k], cc.x, t);
      mn[k] = fminf(mn[k], t);
    }
  }
#pragma unroll
  for (int k = 0; k < 4; ++k) Mmin[shard * N_PTS + qbase + k * 256] = mn[k];
}

// tau[q] = 21st smallest of the 64 shard minima (d' metric), >= d'_(21) incl self
__global__ __launch_bounds__(256) void knn_tau(const float* __restrict__ Mmin,
                                               float* __restrict__ tau) {
  int q = blockIdx.x * 256 + threadIdx.x;
  float a[21];
#pragma unroll
  for (int j = 0; j < 21; ++j) a[j] = 3.4e38f;
  for (int s = 0; s < 64; ++s) {
    float v = Mmin[s * N_PTS + q];
    a[20] = fminf(a[20], v);
#pragma unroll
    for (int j = 20; j >= 1; --j) {  // sink pass restores sortedness
      float lo = fminf(a[j - 1], a[j]), hi = fmaxf(a[j - 1], a[j]);
      a[j - 1] = lo; a[j] = hi;
    }
  }
  tau[q] = a[20];
}

// grid (64 cand-shards, 16 q-groups), block 256, 4 queries/thread.
// Hot loop is ONLY 3 fma + 1 cmp per (cand,query); all survivor handling
// (dist2, key pack, register double-buffer) sits behind a wave-level
// __any() branch (s_cbranch_vccz skips it ~89% of iterations) so the
// compiler cannot if-convert it onto the unconditional path (r7 lesson:
// if-converted survivor code tripled the VALU cost). End-flush: one
// batched atomicAdd per non-empty (query,shard); overflow >2 rare.
__global__ __launch_bounds__(256) void knn_collect(const float4* __restrict__ pos4,
                                                   const float* __restrict__ tau,
                                                   int* __restrict__ cnt,
                                                   unsigned long long* __restrict__ surv) {
  __shared__ float4 cp[256];
  int cbase = blockIdx.x * 256;
  int qbase = blockIdx.y * 1024 + threadIdx.x;
  cp[threadIdx.x] = pos4[cbase + threadIdx.x];
  float4 qp[4];
  float m2x[4], m2y[4], m2z[4], tq[4];
  unsigned long long b0[4], b1[4];
  int sl[4];
#pragma unroll
  for (int k = 0; k < 4; ++k) {
    qp[k] = pos4[qbase + k * 256];
    m2x[k] = -2.f * qp[k].x; m2y[k] = -2.f * qp[k].y; m2z[k] = -2.f * qp[k].z;
    tq[k] = tau[qbase + k * 256] + 2e-4f;  // slack >> worst-case fma rounding
    sl[k] = 0; b0[k] = 0; b1[k] = 0;
  }
  __syncthreads();
  for (int c = 0; c < 256; ++c) {
    float4 cc = cp[c];
#pragma unroll
    for (int k = 0; k < 4; ++k) {
      float t = fmaf(m2z[k], cc.z, cc.w);
      t = fmaf(m2y[k], cc.y, t);
      t = fmaf(m2x[k], cc.x, t);
      bool hit = (t <= tq[k]);
      if (__any(hit)) {        // wave-uniform branch; rare taken
        if (hit) {             // per-lane cold path
          float d = dist2(qp[k], cc);  // exact key, same formula as r4-passing
          unsigned long long key =
              ((unsigned long long)__float_as_uint(d) << 32) |
              (unsigned)(cbase + c);
          if (sl[k] == 0) {
            b0[k] = key; sl[k] = 1;
          } else if (sl[k] == 1) {
            b1[k] = key; sl[k] = 2;
          } else {  // rare overflow: immediate atomic
            int q = qbase + k * 256;
            int slot = atomicAdd(&cnt[q], 1);
            if (slot < 128) surv[(size_t)q * 128 + slot] = key;
          }
        }
      }
    }
  }
  // flush buffered survivors: one atomic per non-empty (query,shard)
#pragma unroll
  for (int k = 0; k < 4; ++k) {
    if (sl[k] > 0) {
      int q = qbase + k * 256;
      int slot = atomicAdd(&cnt[q], sl[k]);
      if (slot < 128) surv[(size_t)q * 128 + slot] = b0[k];
      if (sl[k] > 1 && slot + 1 < 128) surv[(size_t)q * 128 + slot + 1] = b1[k];
    }
  }
}

// block = 64 threads per query: rank survivors; ranks 1..20 -> neighbor list
__global__ void knn_rank(const int* __restrict__ cnt,
                         const unsigned long long* __restrict__ surv,
                         int* __restrict__ nbr) {
  __shared__ unsigned long long s[128];
  int q = blockIdx.x;
  int c = min(cnt[q], 128);
  for (int i = threadIdx.x; i < c; i += 64) s[i] = surv[(size_t)q * 128 + i];
  __syncthreads();
  for (int i = threadIdx.x; i < c; i += 64) {
    unsigned long long key = s[i];
    int rank = 0;
    for (int j = 0; j < c; ++j) rank += (s[j] < key);
    if (rank >= 1 && rank <= KNN) nbr[q * KNN + rank - 1] = (int)(key & 0xffffffffu);
  }
}

// ---------------- LayerNorm (wave per row, 256 cols): f32 in -> bf16 out ----

__global__ __launch_bounds__(256) void ln_kernel(const float* __restrict__ xin,
                                                 const float* __restrict__ w,
                                                 const float* __restrict__ b,
                                                 u16* __restrict__ out) {
  int row = blockIdx.x * 4 + (threadIdx.x >> 6);
  int lane = threadIdx.x & 63;
  float4 u = ((const float4*)(xin + row * DIMS))[lane];
  float f[4] = {fin(u.x), fin(u.y), fin(u.z), fin(u.w)};
  float sum = f[0] + f[1] + f[2] + f[3];
  float sq = f[0] * f[0] + f[1] * f[1] + f[2] * f[2] + f[3] * f[3];
#pragma unroll
  for (int o = 32; o > 0; o >>= 1) {
    sum += __shfl_xor(sum, o);
    sq += __shfl_xor(sq, o);
  }
  float mean = sum * (1.f / 256.f);
  float var = fmaxf(sq * (1.f / 256.f) - mean * mean, 0.f);  // guard
  float rs = rsqrtf(var + 1e-5f);
  float4 wv = ((const float4*)w)[lane];
  float4 bv = ((const float4*)b)[lane];
  ushort4 o4;
  o4.x = f2bf(fin((f[0] - mean) * rs * wv.x + bv.x));
  o4.y = f2bf(fin((f[1] - mean) * rs * wv.y + bv.y));
  o4.z = f2bf(fin((f[2] - mean) * rs * wv.z + bv.z));
  o4.w = f2bf(fin((f[3] - mean) * rs * wv.w + bv.w));
  ((ushort4*)(out + row * DIMS))[lane] = o4;
}

// ---------------- MFMA GEMM body: C[M,Nc] = A[M,K](bf16) * B[Nc,K]^T(f32) + bias ----
// B (weights, f32 in HBM) converted to bf16 during LDS staging.
// EPI 0: bias -> bf16 out
// EPI 1: bias + f32 residual -> f32 out
// EPI 2: bias, exact GELU -> bf16 out
template <int EPI>
__device__ __forceinline__ void gemm_body(const u16* __restrict__ A,
                                          const float* __restrict__ B,
                                          const float* __restrict__ bias,
                                          const float* __restrict__ res,
                                          void* __restrict__ out,
                                          int m0, int n0, int Nc, int K) {
  __shared__ __align__(16) u16 Asm[128 * 32];
  __shared__ __align__(16) u16 Bsm[128 * 32];
  const int t = threadIdx.x;
  const int w = t >> 6, lane = t & 63;
  const int quad = lane >> 4, mr = lane & 15;
  const int wm = (w >> 1) * 64, wn = (w & 1) * 64;
  const int r = t >> 2, sseg = t & 3;

  f32x4 acc[4][4];
  const f32x4 zero4 = {0.f, 0.f, 0.f, 0.f};
#pragma unroll
  for (int i = 0; i < 4; ++i)
#pragma unroll
    for (int j = 0; j < 4; ++j) acc[i][j] = zero4;

  const u16* Ab = A + (size_t)(m0 + r) * K + sseg * 8;
  const float* Bb = B + (size_t)(n0 + r) * K + sseg * 8;
  u16x8* AsmT = (u16x8*)(Asm + t * 8);  // row (t>>2), cols (t&3)*8 -> idx t*8
  u16x8* BsmT = (u16x8*)(Bsm + t * 8);

  for (int k0 = 0; k0 < K; k0 += 32) {
    u16x8 a0 = *(const u16x8*)(Ab + k0);
    u16x8 a1 = *(const u16x8*)(Ab + k0 + (size_t)64 * K);
    float4 b0a = *(const float4*)(Bb + k0);
    float4 b0b = *(const float4*)(Bb + k0 + 4);
    float4 b1a = *(const float4*)(Bb + k0 + (size_t)64 * K);
    float4 b1b = *(const float4*)(Bb + k0 + (size_t)64 * K + 4);
    u16x8 b0 = cvt8(b0a, b0b);
    u16x8 b1 = cvt8(b1a, b1b);
    __syncthreads();  // all waves done reading previous tile
    AsmT[0] = a0;
    AsmT[256] = a1;  // +2048 u16
    BsmT[0] = b0;
    BsmT[256] = b1;
    __syncthreads();  // staging visible
    bf16x8 af[4], bfr[4];
#pragma unroll
    for (int i = 0; i < 4; ++i)
      af[i] = *(const bf16x8*)&Asm[(wm + i * 16 + mr) * 32 + quad * 8];
#pragma unroll
    for (int j = 0; j < 4; ++j)
      bfr[j] = *(const bf16x8*)&Bsm[(wn + j * 16 + mr) * 32 + quad * 8];
#pragma unroll
    for (int i = 0; i < 4; ++i)
#pragma unroll
      for (int j = 0; j < 4; ++j)
        acc[i][j] = __builtin_amdgcn_mfma_f32_16x16x32_bf16(af[i], bfr[j], acc[i][j], 0, 0, 0);
  }

  float* outf = (float*)out;
  u16* outb = (u16*)out;
#pragma unroll
  for (int j = 0; j < 4; ++j) {
    int n = n0 + wn + j * 16 + mr;
    float bv = bias[n];
#pragma unroll
    for (int i = 0; i < 4; ++i) {
      int mb = m0 + wm + i * 16 + quad * 4;
#pragma unroll
      for (int rr = 0; rr < 4; ++rr) {
        size_t off = (size_t)(mb + rr) * Nc + n;
        float v = acc[i][j][rr] + bv;
        if (EPI == 0) {
          outb[off] = f2bf(fin(v));
        } else if (EPI == 1) {
          outf[off] = fin(v + res[off]);
        } else {
          float g = 0.5f * v * (1.0f + erff(v * 0.70710678118654752f));
          outb[off] = f2bf(fin(g));
        }
      }
    }
  }
}

template <int EPI>
__global__ __launch_bounds__(256) void gemm_bt(const u16* __restrict__ A,
                                               const float* __restrict__ B,
                                               const float* __restrict__ bias,
                                               const float* __restrict__ res,
                                               void* __restrict__ out,
                                               int Nc, int K) {
  gemm_body<EPI>(A, B, bias, res, out, blockIdx.y * 128, blockIdx.x * 128, Nc, K);
}

// fused QKV: grid.x in [0,6): sel = x>>1 picks W/bias/out, n0 = (x&1)*128
__global__ __launch_bounds__(256) void gemm_qkv(const u16* __restrict__ A,
                                                const float* __restrict__ Wq,
                                                const float* __restrict__ Wk,
                                                const float* __restrict__ Wv,
                                                const float* __restrict__ bq,
                                                const float* __restrict__ bk,
                                                const float* __restrict__ bv,
                                                u16* __restrict__ qo,
                                                u16* __restrict__ ko,
                                                u16* __restrict__ vo) {
  int sel = blockIdx.x >> 1;
  const float* B = (sel == 0) ? Wq : ((sel == 1) ? Wk : Wv);
  const float* bias = (sel == 0) ? bq : ((sel == 1) ? bk : bv);
  u16* out = (sel == 0) ? qo : ((sel == 1) ? ko : vo);
  gemm_body<0>(A, B, bias, nullptr, out, blockIdx.y * 128, (blockIdx.x & 1) * 128,
               DIMS, DIMS);
}

// ---------------- gathered neighborhood attention (bf16 in/out) ----------------

__global__ __launch_bounds__(256) void attn_kernel(const u16* __restrict__ Q,
                                                   const u16* __restrict__ Kb,
                                                   const u16* __restrict__ Vb,
                                                   const int* __restrict__ nbr,
                                                   u16* __restrict__ out) {
  int t = blockIdx.x * 256 + threadIdx.x;
  int p = t >> 3, h = t & 7;
  const u16* qrow = Q + (size_t)p * DIMS + h * HDIM;
  float qf[32];
#pragma unroll
  for (int c = 0; c < 4; ++c) {
    u16x8 u = *(const u16x8*)(qrow + c * 8);
#pragma unroll
    for (int e = 0; e < 8; ++e) qf[c * 8 + e] = bf2f(u[e]);
  }
  int idx[KNN];
#pragma unroll
  for (int j = 0; j < KNN; ++j) {
    int ix = nbr[p * KNN + j];
    idx[j] = (ix < 0 || ix >= N_PTS) ? 0 : ix;  // fault guard
  }
  float sc[KNN];
#pragma unroll
  for (int j = 0; j < KNN; ++j) {
    const u16* kr = Kb + (size_t)idx[j] * DIMS + h * HDIM;
    float acc = 0.f;
#pragma unroll
    for (int c = 0; c < 4; ++c) {
      u16x8 u = *(const u16x8*)(kr + c * 8);
#pragma unroll
      for (int e = 0; e < 8; ++e) acc += qf[c * 8 + e] * bf2f(u[e]);
    }
    sc[j] = fin(acc * SCALE);
  }
  float mx = sc[0];
#pragma unroll
  for (int j = 1; j < KNN; ++j) mx = fmaxf(mx, sc[j]);
  float sum = 0.f;
#pragma unroll
  for (int j = 0; j < KNN; ++j) {
    sc[j] = expf(sc[j] - mx);
    sum += sc[j];
  }
  float inv = 1.f / fmaxf(sum, 1e-30f);
  float o[32];
#pragma unroll
  for (int d = 0; d < 32; ++d) o[d] = 0.f;
#pragma unroll
  for (int j = 0; j < KNN; ++j) {
    float wgt = sc[j] * inv;
    const u16* vr = Vb + (size_t)idx[j] * DIMS + h * HDIM;
#pragma unroll
    for (int c = 0; c < 4; ++c) {
      u16x8 u = *(const u16x8*)(vr + c * 8);
#pragma unroll
      for (int e = 0; e < 8; ++e) o[c * 8 + e] = fmaf(wgt, bf2f(u[e]), o[c * 8 + e]);
    }
  }
  u16* orow = out + (size_t)p * DIMS + h * HDIM;
#pragma unroll
  for (int c = 0; c < 4; ++c) {
    u16x8 u;
#pragma unroll
    for (int e = 0; e < 8; ++e) u[e] = f2bf(fin(o[c * 8 + e]));
    *(u16x8*)(orow + c * 8) = u;
  }
}

// ---------------- launch ----------------
// Workspace layout (peak 56 MiB), liveness-reused; all kernels on one stream.
//   [0,16M)    x1f (f32, t3..t6)        | earlier: qb [0,8M), kb [8,16M)
//   [16M,48M)  hid (bf16, t5..t6)       | earlier: kNN scratch, vb, ao, h
//   [48M,56M)  h2
extern "C" void kernel_launch(void* const* d_in, const int* in_sizes, int n_in,
                              void* d_out, int out_size, void* d_ws, size_t ws_size,
                              hipStream_t stream) {
  const float* x = (const float*)d_in[0];
  const float* positions = (const float*)d_in[1];
  const float* ln1_w = (const float*)d_in[2];
  const float* ln1_b = (const float*)d_in[3];
  const float* Wq = (const float*)d_in[4];
  const float* bq = (const float*)d_in[5];
  const float* Wk = (const float*)d_in[6];
  const float* bk = (const float*)d_in[7];
  const float* Wv = (const float*)d_in[8];
  const float* bv = (const float*)d_in[9];
  const float* Wo = (const float*)d_in[10];
  const float* bo = (const float*)d_in[11];
  const float* ln2_w = (const float*)d_in[12];
  const float* ln2_b = (const float*)d_in[13];
  const float* W1 = (const float*)d_in[14];
  const float* b1 = (const float*)d_in[15];
  const float* W2 = (const float*)d_in[16];
  const float* b2 = (const float*)d_in[17];

  char* w = (char*)d_ws;
  float* x1f = (float*)(w + 0);                   // 16 MiB   [0,16777216)
  u16* hid = (u16*)(w + 16777216);                // 32 MiB   [16777216,50331648)
  u16* h2 = (u16*)(w + 50331648);                 // 8 MiB    [50331648,58720256)
  // kNN scratch inside hid region (dead before hid is written)
  float4* pos4 = (float4*)(w + 16777216);         // 256 KiB
  float* Mmin = (float*)(w + 17039360);           // 4 MiB
  float* tau = (float*)(w + 21233664);            // 64 KiB
  int* cnt = (int*)(w + 21299200);                // 64 KiB
  unsigned long long* surv = (unsigned long long*)(w + 21364736);  // 16 MiB
  int* nbr = (int*)(w + 38141952);                // 1.25 MiB (live until attn)
  u16* h = (u16*)(w + 39452672);                  // 8 MiB (live t1 only)
  // B-phase reuse
  u16* qb = (u16*)(w + 0);                        // 8 MiB (dead before x1f write)
  u16* kb = (u16*)(w + 8388608);                  // 8 MiB
  u16* vb = (u16*)(w + 21364736);                 // 8 MiB (over dead surv half 1)
  u16* ao = (u16*)(w + 29753344);                 // 8 MiB (over dead surv half 2)

  // t0: kNN pipeline
  init_knn<<<dim3(N_PTS / 256), dim3(256), 0, stream>>>(cnt, nbr);
  prep_pos<<<dim3(N_PTS / 256), dim3(256), 0, stream>>>(positions, pos4);
  knn_shardmin<<<dim3(64, 16), dim3(256), 0, stream>>>(pos4, Mmin);
  knn_tau<<<dim3(64), dim3(256), 0, stream>>>(Mmin, tau);
  knn_collect<<<dim3(64, 16), dim3(256), 0, stream>>>(pos4, tau, cnt, surv);
  knn_rank<<<dim3(N_PTS), dim3(64), 0, stream>>>(cnt, surv, nbr);

  // t1: LN1 + fused QKV
  ln_kernel<<<dim3(N_PTS / 4), dim3(256), 0, stream>>>(x, ln1_w, ln1_b, h);
  gemm_qkv<<<dim3(6, 128), dim3(256), 0, stream>>>(h, Wq, Wk, Wv, bq, bk, bv,
                                                   qb, kb, vb);

  // t2: attention; t3: output proj (+residual 1) -> f32
  attn_kernel<<<dim3(N_PTS * HEADS / 256), dim3(256), 0, stream>>>(qb, kb, vb, nbr, ao);
  gemm_bt<1><<<dim3(2, 128), dim3(256), 0, stream>>>(ao, Wo, bo, x, x1f, DIMS, DIMS);

  // t4: LN2; t5/t6: MLP (+residual 2) -> f32 out
  ln_kernel<<<dim3(N_PTS / 4), dim3(256), 0, stream>>>(x1f, ln2_w, ln2_b, h2);
  gemm_bt<2><<<dim3(8, 128), dim3(256), 0, stream>>>(h2, W1, b1, nullptr, hid, MLPH, DIMS);
  gemm_bt<1><<<dim3(2, 128), dim3(256), 0, stream>>>(hid, W2, b2, x1f, (float*)d_out, DIMS, MLPH);
}

// Round 9
// 378.380 us; speedup vs baseline: 1.0828x; 1.0828x over previous
//
#include <hip/hip_runtime.h>
#include <math.h>

#define N_PTS 16384
#define DIMS 256
#define HEADS 8
#define HDIM 32
#define KNN 20
#define MLPH 1024
#define SCALE 0.17677669529663687f  // 32^-0.5

typedef unsigned short u16;
typedef unsigned long long ull;
typedef __attribute__((ext_vector_type(8))) short bf16x8;
typedef __attribute__((ext_vector_type(8))) unsigned short u16x8;
typedef __attribute__((ext_vector_type(4))) float f32x4;

__device__ __forceinline__ float bf2f(u16 u) {
  return __uint_as_float(((unsigned int)u) << 16);
}
__device__ __forceinline__ u16 f2bf(float f) {
  unsigned int u = __float_as_uint(f);
  u += 0x7fffu + ((u >> 16) & 1u);
  return (u16)(u >> 16);
}
// finite-scrub: NaN/Inf -> 0 (cheap insurance)
__device__ __forceinline__ float fin(float v) {
  return __builtin_isfinite(v) ? v : 0.f;
}
__device__ __forceinline__ float dist2(float4 a, float4 b) {
  float dx = a.x - b.x, dy = a.y - b.y, dz = a.z - b.z;
  return dx * dx + dy * dy + dz * dz;
}
__device__ __forceinline__ u16x8 cvt8(float4 a, float4 b) {
  u16x8 o;
  o[0] = f2bf(a.x); o[1] = f2bf(a.y); o[2] = f2bf(a.z); o[3] = f2bf(a.w);
  o[4] = f2bf(b.x); o[5] = f2bf(b.y); o[6] = f2bf(b.z); o[7] = f2bf(b.w);
  return o;
}

// ---------------- init (zero cnt+nbr) + prep_pos fused ----------------

__global__ __launch_bounds__(256) void knn_init(const float* __restrict__ pos,
                                                float4* __restrict__ pos4,
                                                int* __restrict__ cnt,
                                                int* __restrict__ nbr) {
  int i = blockIdx.x * 256 + threadIdx.x;  // i < N_PTS
  cnt[i] = 0;
#pragma unroll
  for (int j = 0; j < KNN; ++j) nbr[i * KNN + j] = 0;
  float x = fin(pos[3 * i]), y = fin(pos[3 * i + 1]), z = fin(pos[3 * i + 2]);
  pos4[i] = make_float4(x, y, z, x * x + y * y + z * z);
}

// ---------------- kNN ----------------
// pos4.w holds |c|^2 so screening uses d' = |c|^2 - 2 q.c  (d' = d - |q|^2,
// a per-query constant shift: order statistics per query are unaffected).

// grid (64 shards, 16 q-groups), block 256, 4 queries/thread.
__global__ __launch_bounds__(256) void knn_shardmin(const float4* __restrict__ pos4,
                                                    float* __restrict__ Mmin) {
  __shared__ float4 cp[256];
  int shard = blockIdx.x;
  int qbase = blockIdx.y * 1024 + threadIdx.x;
  cp[threadIdx.x] = pos4[shard * 256 + threadIdx.x];
  float m2x[4], m2y[4], m2z[4], mn[4];
#pragma unroll
  for (int k = 0; k < 4; ++k) {
    float4 qp = pos4[qbase + k * 256];
    m2x[k] = -2.f * qp.x; m2y[k] = -2.f * qp.y; m2z[k] = -2.f * qp.z;
    mn[k] = 3.4e38f;
  }
  __syncthreads();
#pragma unroll 4
  for (int c = 0; c < 256; ++c) {
    float4 cc = cp[c];
#pragma unroll
    for (int k = 0; k < 4; ++k) {
      float t = fmaf(m2z[k], cc.z, cc.w);
      t = fmaf(m2y[k], cc.y, t);
      t = fmaf(m2x[k], cc.x, t);
      mn[k] = fminf(mn[k], t);
    }
  }
#pragma unroll
  for (int k = 0; k < 4; ++k) Mmin[shard * N_PTS + qbase + k * 256] = mn[k];
}

// tau[q] = 21st smallest of the 64 shard minima (d' metric), >= d'_(21) incl self
__global__ __launch_bounds__(256) void knn_tau(const float* __restrict__ Mmin,
                                               float* __restrict__ tau) {
  int q = blockIdx.x * 256 + threadIdx.x;
  float a[21];
#pragma unroll
  for (int j = 0; j < 21; ++j) a[j] = 3.4e38f;
  for (int s = 0; s < 64; ++s) {
    float v = Mmin[s * N_PTS + q];
    a[20] = fminf(a[20], v);
#pragma unroll
    for (int j = 20; j >= 1; --j) {  // sink pass restores sortedness
      float lo = fminf(a[j - 1], a[j]), hi = fmaxf(a[j - 1], a[j]);
      a[j - 1] = lo; a[j] = hi;
    }
  }
  tau[q] = a[20];
}

// grid (64 cand-shards, 16 q-groups), block 256, 4 queries/thread.
// Hot loop stays BRANCHLESS (r8 lesson: wave-level __any branch cost more
// than if-conversion), but the if-converted payload is only 3 ops:
//   packed = hit ? (packed<<8)|c : packed;  hitcnt += hit;
// (v_lshl_or + v_cndmask + add). Heavy work (exact dist2, key pack,
// atomics) runs post-loop over <=4 unpacked 8-bit indices; hitcnt>4
// (P~1e-4) falls back to a full rescan for that (thread,query).
__global__ __launch_bounds__(256) void knn_collect(const float4* __restrict__ pos4,
                                                   const float* __restrict__ tau,
                                                   int* __restrict__ cnt,
                                                   ull* __restrict__ surv) {
  __shared__ float4 cp[256];
  int cbase = blockIdx.x * 256;
  int qbase = blockIdx.y * 1024 + threadIdx.x;
  cp[threadIdx.x] = pos4[cbase + threadIdx.x];
  float4 qp[4];
  float m2x[4], m2y[4], m2z[4], tq[4];
  unsigned int packed[4];
  int hitcnt[4];
#pragma unroll
  for (int k = 0; k < 4; ++k) {
    qp[k] = pos4[qbase + k * 256];
    m2x[k] = -2.f * qp[k].x; m2y[k] = -2.f * qp[k].y; m2z[k] = -2.f * qp[k].z;
    tq[k] = tau[qbase + k * 256] + 2e-4f;  // slack >> worst-case fma rounding
    packed[k] = 0; hitcnt[k] = 0;
  }
  __syncthreads();
#pragma unroll 4
  for (int c = 0; c < 256; ++c) {
    float4 cc = cp[c];
#pragma unroll
    for (int k = 0; k < 4; ++k) {
      float t = fmaf(m2z[k], cc.z, cc.w);
      t = fmaf(m2y[k], cc.y, t);
      t = fmaf(m2x[k], cc.x, t);
      bool hit = (t <= tq[k]);
      packed[k] = hit ? ((packed[k] << 8) | (unsigned)c) : packed[k];
      hitcnt[k] += hit ? 1 : 0;
    }
  }
  // cold path: materialize keys for recorded hits
#pragma unroll
  for (int k = 0; k < 4; ++k) {
    int hc = hitcnt[k];
    if (hc > 0) {
      int q = qbase + k * 256;
      if (hc <= 4) {
        int slot = atomicAdd(&cnt[q], hc);
        for (int i = 0; i < hc; ++i) {
          int c = (packed[k] >> (8 * i)) & 255;
          float d = dist2(qp[k], cp[c]);  // exact key, same as r4-passing
          ull key = ((ull)__float_as_uint(d) << 32) | (unsigned)(cbase + c);
          if (slot + i < 128) surv[(size_t)q * 128 + slot + i] = key;
        }
      } else {  // overflow: packed lost early hits -> rescan this query
        for (int c = 0; c < 256; ++c) {
          float4 cc = cp[c];
          float t = fmaf(m2z[k], cc.z, cc.w);
          t = fmaf(m2y[k], cc.y, t);
          t = fmaf(m2x[k], cc.x, t);
          if (t <= tq[k]) {
            float d = dist2(qp[k], cc);
            ull key = ((ull)__float_as_uint(d) << 32) | (unsigned)(cbase + c);
            int slot = atomicAdd(&cnt[q], 1);
            if (slot < 128) surv[(size_t)q * 128 + slot] = key;
          }
        }
      }
    }
  }
}

// block = 64 threads per query: rank survivors; ranks 1..20 -> neighbor list
__global__ void knn_rank(const int* __restrict__ cnt,
                         const ull* __restrict__ surv,
                         int* __restrict__ nbr) {
  __shared__ ull s[128];
  int q = blockIdx.x;
  int c = min(cnt[q], 128);
  for (int i = threadIdx.x; i < c; i += 64) s[i] = surv[(size_t)q * 128 + i];
  __syncthreads();
  for (int i = threadIdx.x; i < c; i += 64) {
    ull key = s[i];
    int rank = 0;
    for (int j = 0; j < c; ++j) rank += (s[j] < key);
    if (rank >= 1 && rank <= KNN) nbr[q * KNN + rank - 1] = (int)(key & 0xffffffffu);
  }
}

// ---------------- LayerNorm (wave per row, 256 cols): f32 in -> bf16 out ----

__global__ __launch_bounds__(256) void ln_kernel(const float* __restrict__ xin,
                                                 const float* __restrict__ w,
                                                 const float* __restrict__ b,
                                                 u16* __restrict__ out) {
  int row = blockIdx.x * 4 + (threadIdx.x >> 6);
  int lane = threadIdx.x & 63;
  float4 u = ((const float4*)(xin + row * DIMS))[lane];
  float f[4] = {fin(u.x), fin(u.y), fin(u.z), fin(u.w)};
  float sum = f[0] + f[1] + f[2] + f[3];
  float sq = f[0] * f[0] + f[1] * f[1] + f[2] * f[2] + f[3] * f[3];
#pragma unroll
  for (int o = 32; o > 0; o >>= 1) {
    sum += __shfl_xor(sum, o);
    sq += __shfl_xor(sq, o);
  }
  float mean = sum * (1.f / 256.f);
  float var = fmaxf(sq * (1.f / 256.f) - mean * mean, 0.f);  // guard
  float rs = rsqrtf(var + 1e-5f);
  float4 wv = ((const float4*)w)[lane];
  float4 bv = ((const float4*)b)[lane];
  ushort4 o4;
  o4.x = f2bf(fin((f[0] - mean) * rs * wv.x + bv.x));
  o4.y = f2bf(fin((f[1] - mean) * rs * wv.y + bv.y));
  o4.z = f2bf(fin((f[2] - mean) * rs * wv.z + bv.z));
  o4.w = f2bf(fin((f[3] - mean) * rs * wv.w + bv.w));
  ((ushort4*)(out + row * DIMS))[lane] = o4;
}

// ---------------- MFMA GEMM body: C[M,Nc] = A[M,K](bf16) * B[Nc,K]^T(f32) + bias ----
// B (weights, f32 in HBM) converted to bf16 during LDS staging.
// EPI 0: bias -> bf16 out
// EPI 1: bias + f32 residual -> f32 out
// EPI 2: bias, exact GELU -> bf16 out
template <int EPI>
__device__ __forceinline__ void gemm_body(const u16* __restrict__ A,
                                          const float* __restrict__ B,
                                          const float* __restrict__ bias,
                                          const float* __restrict__ res,
                                          void* __restrict__ out,
                                          int m0, int n0, int Nc, int K) {
  __shared__ __align__(16) u16 Asm[128 * 32];
  __shared__ __align__(16) u16 Bsm[128 * 32];
  const int t = threadIdx.x;
  const int w = t >> 6, lane = t & 63;
  const int quad = lane >> 4, mr = lane & 15;
  const int wm = (w >> 1) * 64, wn = (w & 1) * 64;
  const int r = t >> 2, sseg = t & 3;

  f32x4 acc[4][4];
  const f32x4 zero4 = {0.f, 0.f, 0.f, 0.f};
#pragma unroll
  for (int i = 0; i < 4; ++i)
#pragma unroll
    for (int j = 0; j < 4; ++j) acc[i][j] = zero4;

  const u16* Ab = A + (size_t)(m0 + r) * K + sseg * 8;
  const float* Bb = B + (size_t)(n0 + r) * K + sseg * 8;
  u16x8* AsmT = (u16x8*)(Asm + t * 8);  // row (t>>2), cols (t&3)*8 -> idx t*8
  u16x8* BsmT = (u16x8*)(Bsm + t * 8);

  for (int k0 = 0; k0 < K; k0 += 32) {
    u16x8 a0 = *(const u16x8*)(Ab + k0);
    u16x8 a1 = *(const u16x8*)(Ab + k0 + (size_t)64 * K);
    float4 b0a = *(const float4*)(Bb + k0);
    float4 b0b = *(const float4*)(Bb + k0 + 4);
    float4 b1a = *(const float4*)(Bb + k0 + (size_t)64 * K);
    float4 b1b = *(const float4*)(Bb + k0 + (size_t)64 * K + 4);
    u16x8 b0 = cvt8(b0a, b0b);
    u16x8 b1 = cvt8(b1a, b1b);
    __syncthreads();  // all waves done reading previous tile
    AsmT[0] = a0;
    AsmT[256] = a1;  // +2048 u16
    BsmT[0] = b0;
    BsmT[256] = b1;
    __syncthreads();  // staging visible
    bf16x8 af[4], bfr[4];
#pragma unroll
    for (int i = 0; i < 4; ++i)
      af[i] = *(const bf16x8*)&Asm[(wm + i * 16 + mr) * 32 + quad * 8];
#pragma unroll
    for (int j = 0; j < 4; ++j)
      bfr[j] = *(const bf16x8*)&Bsm[(wn + j * 16 + mr) * 32 + quad * 8];
#pragma unroll
    for (int i = 0; i < 4; ++i)
#pragma unroll
      for (int j = 0; j < 4; ++j)
        acc[i][j] = __builtin_amdgcn_mfma_f32_16x16x32_bf16(af[i], bfr[j], acc[i][j], 0, 0, 0);
  }

  float* outf = (float*)out;
  u16* outb = (u16*)out;
#pragma unroll
  for (int j = 0; j < 4; ++j) {
    int n = n0 + wn + j * 16 + mr;
    float bv = bias[n];
#pragma unroll
    for (int i = 0; i < 4; ++i) {
      int mb = m0 + wm + i * 16 + quad * 4;
#pragma unroll
      for (int rr = 0; rr < 4; ++rr) {
        size_t off = (size_t)(mb + rr) * Nc + n;
        float v = acc[i][j][rr] + bv;
        if (EPI == 0) {
          outb[off] = f2bf(fin(v));
        } else if (EPI == 1) {
          outf[off] = fin(v + res[off]);
        } else {
          float g = 0.5f * v * (1.0f + erff(v * 0.70710678118654752f));
          outb[off] = f2bf(fin(g));
        }
      }
    }
  }
}

template <int EPI>
__global__ __launch_bounds__(256) void gemm_bt(const u16* __restrict__ A,
                                               const float* __restrict__ B,
                                               const float* __restrict__ bias,
                                               const float* __restrict__ res,
                                               void* __restrict__ out,
                                               int Nc, int K) {
  gemm_body<EPI>(A, B, bias, res, out, blockIdx.y * 128, blockIdx.x * 128, Nc, K);
}

// fused QKV: grid.x in [0,6): sel = x>>1 picks W/bias/out, n0 = (x&1)*128
__global__ __launch_bounds__(256) void gemm_qkv(const u16* __restrict__ A,
                                                const float* __restrict__ Wq,
                                                const float* __restrict__ Wk,
                                                const float* __restrict__ Wv,
                                                const float* __restrict__ bq,
                                                const float* __restrict__ bk,
                                                const float* __restrict__ bv,
                                                u16* __restrict__ qo,
                                                u16* __restrict__ ko,
                                                u16* __restrict__ vo) {
  int sel = blockIdx.x >> 1;
  const float* B = (sel == 0) ? Wq : ((sel == 1) ? Wk : Wv);
  const float* bias = (sel == 0) ? bq : ((sel == 1) ? bk : bv);
  u16* out = (sel == 0) ? qo : ((sel == 1) ? ko : vo);
  gemm_body<0>(A, B, bias, nullptr, out, blockIdx.y * 128, (blockIdx.x & 1) * 128,
               DIMS, DIMS);
}

// ---------------- gathered neighborhood attention (bf16 in/out) ----------------

__global__ __launch_bounds__(256) void attn_kernel(const u16* __restrict__ Q,
                                                   const u16* __restrict__ Kb,
                                                   const u16* __restrict__ Vb,
                                                   const int* __restrict__ nbr,
                                                   u16* __restrict__ out) {
  int t = blockIdx.x * 256 + threadIdx.x;
  int p = t >> 3, h = t & 7;
  const u16* qrow = Q + (size_t)p * DIMS + h * HDIM;
  float qf[32];
#pragma unroll
  for (int c = 0; c < 4; ++c) {
    u16x8 u = *(const u16x8*)(qrow + c * 8);
#pragma unroll
    for (int e = 0; e < 8; ++e) qf[c * 8 + e] = bf2f(u[e]);
  }
  int idx[KNN];
#pragma unroll
  for (int j = 0; j < KNN; ++j) {
    int ix = nbr[p * KNN + j];
    idx[j] = (ix < 0 || ix >= N_PTS) ? 0 : ix;  // fault guard
  }
  float sc[KNN];
#pragma unroll
  for (int j = 0; j < KNN; ++j) {
    const u16* kr = Kb + (size_t)idx[j] * DIMS + h * HDIM;
    float acc = 0.f;
#pragma unroll
    for (int c = 0; c < 4; ++c) {
      u16x8 u = *(const u16x8*)(kr + c * 8);
#pragma unroll
      for (int e = 0; e < 8; ++e) acc += qf[c * 8 + e] * bf2f(u[e]);
    }
    sc[j] = fin(acc * SCALE);
  }
  float mx = sc[0];
#pragma unroll
  for (int j = 1; j < KNN; ++j) mx = fmaxf(mx, sc[j]);
  float sum = 0.f;
#pragma unroll
  for (int j = 0; j < KNN; ++j) {
    sc[j] = expf(sc[j] - mx);
    sum += sc[j];
  }
  float inv = 1.f / fmaxf(sum, 1e-30f);
  float o[32];
#pragma unroll
  for (int d = 0; d < 32; ++d) o[d] = 0.f;
#pragma unroll
  for (int j = 0; j < KNN; ++j) {
    float wgt = sc[j] * inv;
    const u16* vr = Vb + (size_t)idx[j] * DIMS + h * HDIM;
#pragma unroll
    for (int c = 0; c < 4; ++c) {
      u16x8 u = *(const u16x8*)(vr + c * 8);
#pragma unroll
      for (int e = 0; e < 8; ++e) o[c * 8 + e] = fmaf(wgt, bf2f(u[e]), o[c * 8 + e]);
    }
  }
  u16* orow = out + (size_t)p * DIMS + h * HDIM;
#pragma unroll
  for (int c = 0; c < 4; ++c) {
    u16x8 u;
#pragma unroll
    for (int e = 0; e < 8; ++e) u[e] = f2bf(fin(o[c * 8 + e]));
    *(u16x8*)(orow + c * 8) = u;
  }
}

// ---------------- launch ----------------
// Workspace layout (peak 56 MiB), liveness-reused; all kernels on one stream.
//   [0,16M)    x1f (f32, t3..t6)        | earlier: qb [0,8M), kb [8,16M)
//   [16M,48M)  hid (bf16, t5..t6)       | earlier: kNN scratch, vb, ao, h
//   [48M,56M)  h2
extern "C" void kernel_launch(void* const* d_in, const int* in_sizes, int n_in,
                              void* d_out, int out_size, void* d_ws, size_t ws_size,
                              hipStream_t stream) {
  const float* x = (const float*)d_in[0];
  const float* positions = (const float*)d_in[1];
  const float* ln1_w = (const float*)d_in[2];
  const float* ln1_b = (const float*)d_in[3];
  const float* Wq = (const float*)d_in[4];
  const float* bq = (const float*)d_in[5];
  const float* Wk = (const float*)d_in[6];
  const float* bk = (const float*)d_in[7];
  const float* Wv = (const float*)d_in[8];
  const float* bv = (const float*)d_in[9];
  const float* Wo = (const float*)d_in[10];
  const float* bo = (const float*)d_in[11];
  const float* ln2_w = (const float*)d_in[12];
  const float* ln2_b = (const float*)d_in[13];
  const float* W1 = (const float*)d_in[14];
  const float* b1 = (const float*)d_in[15];
  const float* W2 = (const float*)d_in[16];
  const float* b2 = (const float*)d_in[17];

  char* w = (char*)d_ws;
  float* x1f = (float*)(w + 0);                   // 16 MiB   [0,16777216)
  u16* hid = (u16*)(w + 16777216);                // 32 MiB   [16777216,50331648)
  u16* h2 = (u16*)(w + 50331648);                 // 8 MiB    [50331648,58720256)
  // kNN scratch inside hid region (dead before hid is written)
  float4* pos4 = (float4*)(w + 16777216);         // 256 KiB
  float* Mmin = (float*)(w + 17039360);           // 4 MiB
  float* tau = (float*)(w + 21233664);            // 64 KiB
  int* cnt = (int*)(w + 21299200);                // 64 KiB
  ull* surv = (ull*)(w + 21364736);               // 16 MiB
  int* nbr = (int*)(w + 38141952);                // 1.25 MiB (live until attn)
  u16* h = (u16*)(w + 39452672);                  // 8 MiB (live t1 only)
  // B-phase reuse
  u16* qb = (u16*)(w + 0);                        // 8 MiB (dead before x1f write)
  u16* kb = (u16*)(w + 8388608);                  // 8 MiB
  u16* vb = (u16*)(w + 21364736);                 // 8 MiB (over dead surv half 1)
  u16* ao = (u16*)(w + 29753344);                 // 8 MiB (over dead surv half 2)

  // t0: kNN pipeline
  knn_init<<<dim3(N_PTS / 256), dim3(256), 0, stream>>>(positions, pos4, cnt, nbr);
  knn_shardmin<<<dim3(64, 16), dim3(256), 0, stream>>>(pos4, Mmin);
  knn_tau<<<dim3(64), dim3(256), 0, stream>>>(Mmin, tau);
  knn_collect<<<dim3(64, 16), dim3(256), 0, stream>>>(pos4, tau, cnt, surv);
  knn_rank<<<dim3(N_PTS), dim3(64), 0, stream>>>(cnt, surv, nbr);

  // t1: LN1 + fused QKV
  ln_kernel<<<dim3(N_PTS / 4), dim3(256), 0, stream>>>(x, ln1_w, ln1_b, h);
  gemm_qkv<<<dim3(6, 128), dim3(256), 0, stream>>>(h, Wq, Wk, Wv, bq, bk, bv,
                                                   qb, kb, vb);

  // t2: attention; t3: output proj (+residual 1) -> f32
  attn_kernel<<<dim3(N_PTS * HEADS / 256), dim3(256), 0, stream>>>(qb, kb, vb, nbr, ao);
  gemm_bt<1><<<dim3(2, 128), dim3(256), 0, stream>>>(ao, Wo, bo, x, x1f, DIMS, DIMS);

  // t4: LN2; t5/t6: MLP (+residual 2) -> f32 out
  ln_kernel<<<dim3(N_PTS / 4), dim3(256), 0, stream>>>(x1f, ln2_w, ln2_b, h2);
  gemm_bt<2><<<dim3(8, 128), dim3(256), 0, stream>>>(h2, W1, b1, nullptr, hid, MLPH, DIMS);
  gemm_bt<1><<<dim3(2, 128), dim3(256), 0, stream>>>(hid, W2, b2, x1f, (float*)d_out, DIMS, MLPH);
}